// Round 17
// baseline (60.216 us; speedup 1.0000x reference)
//
#include <hip/hip_runtime.h>

typedef __attribute__((ext_vector_type(8))) short short8;
typedef __attribute__((ext_vector_type(4))) float f32x4;

#define MFMA_16x16x32_BF16(A, B, C) __builtin_amdgcn_mfma_f32_16x16x32_bf16(A, B, C, 0, 0, 0)

// float -> bf16 bits, round-to-nearest-even (inputs always finite here)
__device__ __forceinline__ unsigned short f2bf(float x) {
    unsigned int u = __builtin_bit_cast(unsigned int, x);
    u = (u + 0x7FFFu + ((u >> 16) & 1u)) >> 16;
    return (unsigned short)u;
}

// ---------------------------------------------------------------------------
// Kernel 1: pack Wk|Wq|Wv (fp32 [1024][64]) -> Wt bf16 [192][1024] transposed,
// with the proj LDS bank-swizzle PRE-BAKED: within each 64-k tile, 8-short
// chunk c holds logical chunk c ^ (n&7).  (G21: glds writes LDS linearly, so
// the conflict-free permutation must come from the source.)
// ---------------------------------------------------------------------------
__global__ __launch_bounds__(256) void wconv_kernel(const float* __restrict__ Wk,
                                                    const float* __restrict__ Wq,
                                                    const float* __restrict__ Wv,
                                                    unsigned short* __restrict__ Wt) {
    const int n = blockIdx.x;                       // 0..191
    const float* W = (n < 64) ? Wk : (n < 128) ? Wq : Wv;
    const int col = n & 63;
    const int sw = (n & 7) << 3;
    for (int k = threadIdx.x; k < 1024; k += 256) {
        const int kd = (k & ~56) | ((k ^ sw) & 56);   // XOR chunk bits 3..5
        Wt[(size_t)n * 1024 + kd] = f2bf(W[(size_t)k * 64 + col]);
    }
}

// ---------------------------------------------------------------------------
// Kernel 1b: X fp32 [16384][1024] -> Xb bf16 [16384][1024] row-major with the
// proj A-swizzle PRE-BAKED per 64-short k-tile (chunk cl stored at
// cl^(arow&7)).  Pure contiguous streaming: block = 4 FULL rows (r16 bug:
// covered only half of 8 rows); 512 chunks = 256 thr x 2 iters; each wave
// reads 2KB contiguous, writes 1KB contiguous (permutation intra-128B only).
// Grid 4096 = 16 blocks/CU.  Moves the 67MB X read OUT of the GEMM's
// dependent stage/drain chain (which capped in-loop X at ~1.7 TB/s while
// trivial copies hit 6.7 TB/s).
// ---------------------------------------------------------------------------
__global__ __launch_bounds__(256) void xconv_kernel(const float* __restrict__ X,
                                                    unsigned short* __restrict__ Xb) {
    const int t = threadIdx.x;
    const size_t base = (size_t)blockIdx.x * 4 * 1024;   // 4 rows/block
#pragma unroll
    for (int i = 0; i < 2; ++i) {
        const int q = t + 256 * i;                 // 0..511
        const int row = q >> 7, c = q & 127;       // local row 0..3, 32B-chunk 0..127
        const float* src = X + base + (size_t)row * 1024 + c * 8;
        float4 v0 = *(const float4*)src;
        float4 v1 = *(const float4*)(src + 4);
        uint4 o;
        o.x = (unsigned)f2bf(v0.x) | ((unsigned)f2bf(v0.y) << 16);
        o.y = (unsigned)f2bf(v0.z) | ((unsigned)f2bf(v0.w) << 16);
        o.z = (unsigned)f2bf(v1.x) | ((unsigned)f2bf(v1.y) << 16);
        o.w = (unsigned)f2bf(v1.z) | ((unsigned)f2bf(v1.w) << 16);
        const int kt = c >> 3, cl = c & 7;
        const int arow = (blockIdx.x * 4 + row) & 7;     // ABSOLUTE row & 7
        *(uint4*)&Xb[base + (size_t)row * 1024 + kt * 64 + (cl ^ arow) * 8] = o;
    }
}

// ---------------------------------------------------------------------------
// Kernel 2: QKV projection GEMM — T3 minimum 2-phase, ALL-glds, ZERO in-loop
// HBM.  BM=32, BN=192, BK=64; 512 thr = 8 waves (rw=w>>2 row-half, cw=w&3
// col-quarter); grid 512 = 2 blocks/CU (56KB LDS).  Per iter t:
//   [STAGE buf^1 <- glds A(t+1) 4KB + W(t+1) 24KB, both L3/L2-resident bf16]
//   [compute tile t from buf]                 <- glds fly under the MFMAs
//   [__syncthreads: drains the L2-latency glds; one barrier/iter]
// Both LDS tiles source-swizzled (wconv/xconv) -> conflict-free b128 reads,
// linear glds dest.
// ---------------------------------------------------------------------------
__global__ __launch_bounds__(512, 2) void proj_kernel(const unsigned short* __restrict__ Xb,
                                                      const unsigned short* __restrict__ Wt,
                                                      unsigned short* __restrict__ Kb,
                                                      unsigned short* __restrict__ Qb,
                                                      unsigned short* __restrict__ Vt2) {
    __shared__ __attribute__((aligned(16))) unsigned short Wl[2][192 * 64];  // 48KB
    __shared__ __attribute__((aligned(16))) unsigned short Al[2][32 * 64];   // 8KB
    const int t = threadIdx.x;
    const int w = t >> 6, lane = t & 63, lr = lane & 15, g = lane >> 4;
    const int rw = w >> 2, cw = w & 3;
    const int r0 = blockIdx.x * 32;

    f32x4 acc[3] = {};

    auto STAGE = [&](int buf, int t16) {
        const int k0 = t16 * 64;
#pragma unroll
        for (int i = 0; i < 3; ++i) {              // W: 1536 16B chunks
            const int q = t + 512 * i;
            const unsigned short* src = Wt + (size_t)(q >> 3) * 1024 + k0 + (q & 7) * 8;
            __builtin_amdgcn_global_load_lds((const __attribute__((address_space(1))) void*)src,
                                             (__attribute__((address_space(3))) void*)&Wl[buf][q * 8],
                                             16, 0, 0);
        }
        if (t < 256) {                             // A: 256 16B chunks (wave-uniform guard)
            const int row = t >> 3, cl = t & 7;
            const unsigned short* src = Xb + (size_t)(r0 + row) * 1024 + k0 + cl * 8;
            __builtin_amdgcn_global_load_lds((const __attribute__((address_space(1))) void*)src,
                                             (__attribute__((address_space(3))) void*)&Al[buf][t * 8],
                                             16, 0, 0);
        }
    };

    STAGE(0, 0);
    __syncthreads();                               // tile 0 ready

    for (int t16 = 0; t16 < 16; ++t16) {
        const int cur = t16 & 1;
        if (t16 < 15) STAGE(cur ^ 1, t16 + 1);     // glds fly under compute

        // ---- compute tile t from buf cur ----
        short8 af[2];
#pragma unroll
        for (int sub = 0; sub < 2; ++sub) {
            const int cs = (4 * sub + g) ^ (lr & 7);         // un-swizzle A
            af[sub] = *(const short8*)&Al[cur][(16 * rw + lr) * 64 + cs * 8];
        }
#pragma unroll
        for (int c = 0; c < 3; ++c) {
            const int row = 48 * cw + 16 * c + lr;
#pragma unroll
            for (int sub = 0; sub < 2; ++sub) {
                const int cs = (4 * sub + g) ^ (lr & 7);     // un-swizzle W
                short8 wf = *(const short8*)&Wl[cur][row * 64 + cs * 8];
                acc[c] = MFMA_16x16x32_BF16(af[sub], wf, acc[c]);
            }
        }
        if (t16 < 15) __syncthreads();             // drains t+1 glds (one barrier/iter)
    }

    // ---- epilogue: C/D layout col = lane&15 (W-col), row = 4*(lane>>4)+reg ----
    const int bb = r0 >> 11;                      // batch
    const int row = r0 + 16 * rw + 4 * g;
#pragma unroll
    for (int i = 0; i < 3; ++i) {
        const int cg = cw * 3 + i;                // global col-tile 0..11
        if (cg < 4) {
#pragma unroll
            for (int r = 0; r < 4; ++r)
                Kb[(size_t)(row + r) * 64 + 16 * cg + lr] = f2bf(acc[i][r]);
        } else if (cg < 8) {
#pragma unroll
            for (int r = 0; r < 4; ++r)
                Qb[(size_t)(row + r) * 64 + 16 * (cg - 4) + lr] = f2bf(acc[i][r]);
        } else {
            // Vt2 sigma-interleaved: [b][h][kt][g][e]; kt=(r0&2047)>>5, e0=4*rw.
            const int h = 16 * (cg - 8) + lr;
            uint2 e;
            e.x = (unsigned)f2bf(acc[i][0]) | ((unsigned)f2bf(acc[i][1]) << 16);
            e.y = (unsigned)f2bf(acc[i][2]) | ((unsigned)f2bf(acc[i][3]) << 16);
            *(uint2*)(Vt2 + (size_t)bb * 64 * 2048 + (size_t)h * 2048
                      + ((r0 & 2047) >> 5) * 32 + g * 8 + 4 * rw) = e;
        }
    }
}

// ---------------------------------------------------------------------------
// Kernel 3: causal flash attention (r15 measured-best, verbatim).
// Band-pair blocks + 2-step load batching + 16B V-frag loads (Vt2 layout).
// ---------------------------------------------------------------------------
__global__ __launch_bounds__(512, 2) void attn_kernel(const unsigned short* __restrict__ Kb,
                                                      const unsigned short* __restrict__ Qb,
                                                      const unsigned short* __restrict__ Vt2,
                                                      float* __restrict__ out) {
    __shared__ __attribute__((aligned(16))) float Pacc[16][32][68];  // [slot][q][h] pad 68
    __shared__ float Pml[2][16][32];                                 // m / l per slot,q

    const int t = threadIdx.x;
    const int w = t >> 6, lane = t & 63;
    const int lr = lane & 15, g = lane >> 4;
    const int p = blockIdx.x, b = blockIdx.y;
    const int nhi = 64 - p;                      // steps for hi band
    const int q0h = (63 - p) * 32, q0l = p * 32;
    const size_t rowbase = (size_t)b * 2048;
    const size_t vbase = (size_t)b * 64 * 2048;
    const float NEG_INF = -__builtin_inff();
    const float SCALE2 = 0.03125f * 1.4426950408889634f;   // d^-0.5 * log2(e)

    // Q fragments (B-operand): [sub][hh]
    short8 qfH[2][2], qfL[2][2];
#pragma unroll
    for (int sub = 0; sub < 2; ++sub)
#pragma unroll
        for (int hh = 0; hh < 2; ++hh) {
            qfH[sub][hh] = *(const short8*)(Qb + (rowbase + q0h + 16 * sub + lr) * 64 + 32 * hh + 8 * g);
            qfL[sub][hh] = *(const short8*)(Qb + (rowbase + q0l + 16 * sub + lr) * 64 + 32 * hh + 8 * g);
        }

    f32x4 accH[2][4] = {}, accL[2][4] = {};
    float mH[2] = {NEG_INF, NEG_INF}, mL[2] = {NEG_INF, NEG_INF};
    float lH[2] = {0.f, 0.f}, lL[2] = {0.f, 0.f};

    const int s0 = (w * 65) >> 3, s1 = ((w + 1) * 65) >> 3;

    auto loadS = [&](int kv0, short8 (&kf)[2][2], short8 (&vf)[4]) {
#pragma unroll
        for (int f = 0; f < 2; ++f)
#pragma unroll
            for (int hh = 0; hh < 2; ++hh)
                kf[f][hh] = *(const short8*)(Kb + (rowbase + kv0 + 16 * f + lr) * 64 + 32 * hh + 8 * g);
#pragma unroll
        for (int fh = 0; fh < 4; ++fh)
            vf[fh] = *(const short8*)(Vt2 + vbase + (size_t)(16 * fh + lr) * 2048 + (kv0 >> 5) * 32 + 8 * g);
    };

    auto comp = [&](int kv0, int q0, const short8 (&qf)[2][2],
                    const short8 (&kf)[2][2], const short8 (&vf)[4],
                    f32x4 (&acc)[2][4], float (&m2)[2], float (&ls)[2]) {
#pragma unroll
        for (int sub = 0; sub < 2; ++sub) {
            f32x4 sv[2];
#pragma unroll
            for (int f = 0; f < 2; ++f) {
                f32x4 x = {};
                x = MFMA_16x16x32_BF16(kf[f][0], qf[sub][0], x);
                x = MFMA_16x16x32_BF16(kf[f][1], qf[sub][1], x);
                sv[f] = x;
            }
            const int q = q0 + 16 * sub + lr;
            float pvv[8], tmax = NEG_INF;
#pragma unroll
            for (int f = 0; f < 2; ++f)
#pragma unroll
                for (int r = 0; r < 4; ++r) {
                    int kp = kv0 + 16 * f + 4 * g + r;
                    float sc = sv[f][r] * SCALE2;
                    sc = (kp <= q) ? sc : NEG_INF;
                    pvv[4 * f + r] = sc;
                    tmax = fmaxf(tmax, sc);
                }
            tmax = fmaxf(tmax, __shfl_xor(tmax, 16));
            tmax = fmaxf(tmax, __shfl_xor(tmax, 32));
            float mnew = fmaxf(m2[sub], tmax);     // finite: kv0 <= q0 <= q always
            float alpha = exp2f(m2[sub] - mnew);
            float psum = 0.f;
            short8 pf;
#pragma unroll
            for (int e = 0; e < 8; ++e) {
                float pe = exp2f(pvv[e] - mnew);
                psum += pe;
                pf[e] = (short)f2bf(pe);
            }
            psum += __shfl_xor(psum, 16);
            psum += __shfl_xor(psum, 32);
            ls[sub] = ls[sub] * alpha + psum;
            m2[sub] = mnew;
#pragma unroll
            for (int fh = 0; fh < 4; ++fh) {
                acc[sub][fh][0] *= alpha; acc[sub][fh][1] *= alpha;
                acc[sub][fh][2] *= alpha; acc[sub][fh][3] *= alpha;
                acc[sub][fh] = MFMA_16x16x32_BF16(vf[fh], pf, acc[sub][fh]);
            }
        }
    };

    short8 kfA[2][2], vfA[4], kfB[2][2], vfB[4];

    // ---- hi band (kv0 = s*32) ----
    {
        const int e = (s1 < nhi) ? s1 : nhi;
        int s = s0;
        for (; s + 1 < e; s += 2) {
            loadS(s * 32, kfA, vfA);
            loadS((s + 1) * 32, kfB, vfB);       // flies under comp(A)
            comp(s * 32, q0h, qfH, kfA, vfA, accH, mH, lH);
            comp((s + 1) * 32, q0h, qfH, kfB, vfB, accH, mH, lH);
        }
        if (s < e) {
            loadS(s * 32, kfA, vfA);
            comp(s * 32, q0h, qfH, kfA, vfA, accH, mH, lH);
        }
    }
    // ---- lo band (kv0 = (s-nhi)*32) ----
    {
        int s = (s0 > nhi) ? s0 : nhi;
        for (; s + 1 < s1; s += 2) {
            loadS((s - nhi) * 32, kfA, vfA);
            loadS((s + 1 - nhi) * 32, kfB, vfB);
            comp((s - nhi) * 32, q0l, qfL, kfA, vfA, accL, mL, lL);
            comp((s + 1 - nhi) * 32, q0l, qfL, kfB, vfB, accL, mL, lL);
        }
        if (s < s1) {
            loadS((s - nhi) * 32, kfA, vfA);
            comp((s - nhi) * 32, q0l, qfL, kfA, vfA, accL, mL, lL);
        }
    }

    // ---- write partials to LDS ----
#pragma unroll
    for (int bnd = 0; bnd < 2; ++bnd) {
        const f32x4 (&acc)[2][4] = bnd ? accL : accH;
        const float (&m2)[2] = bnd ? mL : mH;
        const float (&ls)[2] = bnd ? lL : lH;
        const int slot = bnd * 8 + w;
#pragma unroll
        for (int sub = 0; sub < 2; ++sub) {
#pragma unroll
            for (int fh = 0; fh < 4; ++fh)
                *(f32x4*)&Pacc[slot][16 * sub + lr][16 * fh + 4 * g] = acc[sub][fh];
            if (g == 0) {
                Pml[0][slot][16 * sub + lr] = m2[sub];
                Pml[1][slot][16 * sub + lr] = ls[sub];
            }
        }
    }
    __syncthreads();

    // ---- combine: 512 thr -> 2 bands x 32 q x 8 h-groups ----
    {
        const int tb = t >> 8, t2 = t & 255;
        const int qq = t2 & 31, hb = (t2 >> 5) * 8;
        float mw[8], M = NEG_INF;
#pragma unroll
        for (int wv = 0; wv < 8; ++wv) {
            mw[wv] = Pml[0][tb * 8 + wv][qq];
            M = fmaxf(M, mw[wv]);
        }
        float wgt[8], L = 0.f;
#pragma unroll
        for (int wv = 0; wv < 8; ++wv) {
            wgt[wv] = exp2f(mw[wv] - M);           // exp2(-inf)=0 for idle waves
            L += wgt[wv] * Pml[1][tb * 8 + wv][qq];
        }
        f32x4 o0 = {}, o1 = {};
#pragma unroll
        for (int wv = 0; wv < 8; ++wv) {
            f32x4 a0 = *(const f32x4*)&Pacc[tb * 8 + wv][qq][hb];
            f32x4 a1 = *(const f32x4*)&Pacc[tb * 8 + wv][qq][hb + 4];
            o0 += wgt[wv] * a0;
            o1 += wgt[wv] * a1;
        }
        const float invL = 1.f / L;
        o0 *= invL; o1 *= invL;
        const int q0 = tb ? q0l : q0h;
        float* op = out + (rowbase + q0 + qq) * 64 + hb;
        *(f32x4*)op = o0;
        *(f32x4*)(op + 4) = o1;
    }
}

// ---------------------------------------------------------------------------
extern "C" void kernel_launch(void* const* d_in, const int* in_sizes, int n_in,
                              void* d_out, int out_size, void* d_ws, size_t ws_size,
                              hipStream_t stream) {
    const float* X  = (const float*)d_in[0];
    const float* Wk = (const float*)d_in[1];
    const float* Wq = (const float*)d_in[2];
    const float* Wv = (const float*)d_in[3];
    float* out = (float*)d_out;

    unsigned short* Wt  = (unsigned short*)d_ws;       // 192*1024 bf16 (swizzled)
    unsigned short* Xb  = Wt + 192 * 1024;             // [16384][1024] bf16 (swizzled)
    unsigned short* Kb  = Xb + (size_t)16384 * 1024;   // [16384][64] bf16
    unsigned short* Qb  = Kb + 16384 * 64;             // [16384][64] bf16
    unsigned short* Vt2 = Qb + 16384 * 64;             // [8][64][64][32] bf16 (V^T sigma)

    wconv_kernel<<<dim3(192), dim3(256), 0, stream>>>(Wk, Wq, Wv, Wt);
    xconv_kernel<<<dim3(4096), dim3(256), 0, stream>>>(X, Xb);
    proj_kernel<<<dim3(512), dim3(512), 0, stream>>>(Xb, Wt, Kb, Qb, Vt2);
    attn_kernel<<<dim3(32, 8), dim3(512), 0, stream>>>(Kb, Qb, Vt2, out);
}

// Round 18
// 49.025 us; speedup vs baseline: 1.2283x; 1.2283x over previous
//
#include <hip/hip_runtime.h>

typedef __attribute__((ext_vector_type(8))) short short8;
typedef __attribute__((ext_vector_type(4))) float f32x4;

#define MFMA_16x16x32_BF16(A, B, C) __builtin_amdgcn_mfma_f32_16x16x32_bf16(A, B, C, 0, 0, 0)

// float -> bf16 bits, round-to-nearest-even (inputs always finite here)
__device__ __forceinline__ unsigned short f2bf(float x) {
    unsigned int u = __builtin_bit_cast(unsigned int, x);
    u = (u + 0x7FFFu + ((u >> 16) & 1u)) >> 16;
    return (unsigned short)u;
}

// ---------------------------------------------------------------------------
// Kernel 1: pack Wk|Wq|Wv (fp32 [1024][64]) -> Wt bf16 [192][1024] transposed,
// with the proj LDS bank-swizzle PRE-BAKED: within each 64-k tile, 8-short
// chunk c holds logical chunk c ^ (n&7).  (G21: glds writes LDS linearly, so
// the conflict-free permutation must come from the source.)
// ---------------------------------------------------------------------------
__global__ __launch_bounds__(256) void wconv_kernel(const float* __restrict__ Wk,
                                                    const float* __restrict__ Wq,
                                                    const float* __restrict__ Wv,
                                                    unsigned short* __restrict__ Wt) {
    const int n = blockIdx.x;                       // 0..191
    const float* W = (n < 64) ? Wk : (n < 128) ? Wq : Wv;
    const int col = n & 63;
    const int sw = (n & 7) << 3;
    for (int k = threadIdx.x; k < 1024; k += 256) {
        const int kd = (k & ~56) | ((k ^ sw) & 56);   // XOR chunk bits 3..5
        Wt[(size_t)n * 1024 + kd] = f2bf(W[(size_t)k * 64 + col]);
    }
}

// ---------------------------------------------------------------------------
// Kernel 2: QKV projection GEMM — r10 structure (best measured ~34us):
// 2-phase pipeline with COUNTED-VMCNT barrier.  BM=32, BN=192, BK=64;
// 512 thr = 8 waves; grid 512 = 2 blocks/CU.  V epilogue writes the
// sigma-interleaved Vt2 layout (16B V-frag loads in attn).
// ---------------------------------------------------------------------------
__global__ __launch_bounds__(512, 4) void proj_kernel(const float* __restrict__ X,
                                                      const unsigned short* __restrict__ Wt,
                                                      unsigned short* __restrict__ Kb,
                                                      unsigned short* __restrict__ Qb,
                                                      unsigned short* __restrict__ Vt2) {
    __shared__ __attribute__((aligned(16))) unsigned short Wl[2][192 * 64];  // glds dbuf
    __shared__ __attribute__((aligned(16))) unsigned short Al[2][32 * 72];   // pad 64->72
    const int t = threadIdx.x;
    const int w = t >> 6, lane = t & 63, lr = lane & 15, g = lane >> 4;
    const int rw = w >> 2, cw = w & 3;
    const int r0 = blockIdx.x * 32;

    f32x4 acc[3] = {};

    // A staging coords: row = t>>4 (0..31), chunk = t&15 (4 floats)
    const int ar = t >> 4, ac = (t & 15) * 4;
    const float* xsrc = X + (size_t)(r0 + ar) * 1024 + ac;

    // ---- prologue ----
    float4 fly = *(const float4*)xsrc;                     // A(0)
    uint2 aw;
    aw.x = (unsigned)f2bf(fly.x) | ((unsigned)f2bf(fly.y) << 16);
    aw.y = (unsigned)f2bf(fly.z) | ((unsigned)f2bf(fly.w) << 16);
    *(uint2*)&Al[0][ar * 72 + ac] = aw;
#pragma unroll
    for (int i = 0; i < 3; ++i) {                          // W(0) -> Wl[0]
        const int q = t + 512 * i;
        const unsigned short* src = Wt + (size_t)(q >> 3) * 1024 + (q & 7) * 8;
        __builtin_amdgcn_global_load_lds((const __attribute__((address_space(1))) void*)src,
                                         (__attribute__((address_space(3))) void*)&Wl[0][q * 8],
                                         16, 0, 0);
    }
    __builtin_amdgcn_sched_barrier(0);                     // keep A-issue younger than glds
    fly = *(const float4*)(xsrc + 64);                     // A(1) — flies across barrier
    asm volatile("s_waitcnt vmcnt(1) lgkmcnt(0)" ::: "memory");
    __builtin_amdgcn_s_barrier();                          // tiles t=0 ready

    for (int t16 = 0; t16 < 16; ++t16) {
        const int cur = t16 & 1;
        if (t16 < 15) {
            // ---- convert A(t+1): auto-wait drains exactly that load ----
            aw.x = (unsigned)f2bf(fly.x) | ((unsigned)f2bf(fly.y) << 16);
            aw.y = (unsigned)f2bf(fly.z) | ((unsigned)f2bf(fly.w) << 16);
            *(uint2*)&Al[cur ^ 1][ar * 72 + ac] = aw;
            const int k1 = (t16 + 1) * 64;
#pragma unroll
            for (int i = 0; i < 3; ++i) {
                const int q = t + 512 * i;
                const unsigned short* src = Wt + (size_t)(q >> 3) * 1024 + k1 + (q & 7) * 8;
                __builtin_amdgcn_global_load_lds((const __attribute__((address_space(1))) void*)src,
                                                 (__attribute__((address_space(3))) void*)&Wl[cur ^ 1][q * 8],
                                                 16, 0, 0);
            }
            __builtin_amdgcn_sched_barrier(0);             // pin: glds older than A-issue
            const int anext = (t16 + 2 < 15) ? (t16 + 2) : 15;
            fly = *(const float4*)(xsrc + anext * 64);
        }

        // ---- compute tile t from buf cur ----
        short8 af[2];
        af[0] = *(const short8*)&Al[cur][(16 * rw + lr) * 72 + 8 * g];
        af[1] = *(const short8*)&Al[cur][(16 * rw + lr) * 72 + 32 + 8 * g];
#pragma unroll
        for (int c = 0; c < 3; ++c) {
            const int row = 48 * cw + 16 * c + lr;
#pragma unroll
            for (int sub = 0; sub < 2; ++sub) {
                const int cs = (4 * sub + g) ^ (lr & 7);     // un-swizzle
                short8 wf = *(const short8*)&Wl[cur][row * 64 + cs * 8];
                acc[c] = MFMA_16x16x32_BF16(af[sub], wf, acc[c]);
            }
        }
        // ---- counted-vmcnt barrier: W(t+1) drained, A prefetch stays live ----
        asm volatile("s_waitcnt vmcnt(1) lgkmcnt(0)" ::: "memory");
        __builtin_amdgcn_s_barrier();
    }

    // ---- epilogue: C/D layout col = lane&15 (W-col), row = 4*(lane>>4)+reg ----
    const int bb = r0 >> 11;                      // batch
    const int row = r0 + 16 * rw + 4 * g;
#pragma unroll
    for (int i = 0; i < 3; ++i) {
        const int cg = cw * 3 + i;                // global col-tile 0..11
        if (cg < 4) {
#pragma unroll
            for (int r = 0; r < 4; ++r)
                Kb[(size_t)(row + r) * 64 + 16 * cg + lr] = f2bf(acc[i][r]);
        } else if (cg < 8) {
#pragma unroll
            for (int r = 0; r < 4; ++r)
                Qb[(size_t)(row + r) * 64 + 16 * (cg - 4) + lr] = f2bf(acc[i][r]);
        } else {
            // Vt2 sigma-interleaved: [b][h][kt][g][e], e<4 -> kv=32kt+4g+e,
            // e>=4 -> kv=32kt+16+4g+(e-4).  Here kt=(r0&2047)>>5, e0=4*rw.
            const int h = 16 * (cg - 8) + lr;
            uint2 e;
            e.x = (unsigned)f2bf(acc[i][0]) | ((unsigned)f2bf(acc[i][1]) << 16);
            e.y = (unsigned)f2bf(acc[i][2]) | ((unsigned)f2bf(acc[i][3]) << 16);
            *(uint2*)(Vt2 + (size_t)bb * 64 * 2048 + (size_t)h * 2048
                      + ((r0 & 2047) >> 5) * 32 + g * 8 + 4 * rw) = e;
        }
    }
}

// ---------------------------------------------------------------------------
// Kernel 3: causal flash attention, band-pair blocks (r15 measured-best):
// r2 structure + 2-step load batching + 16B V-frag loads (Vt2 layout).
// Block = bands {63-p (hi), p (lo)} of 32 q-rows each -> exactly 65 kv-steps.
// 8 waves split the 65 steps contiguously; K/V frags direct from global
// (L2-resident), loads for a PAIR of steps issued together so step-2's
// loads fly under step-1's compute (in-order vmcnt auto-waits).  Partials
// merged in LDS at the end.
// ---------------------------------------------------------------------------
__global__ __launch_bounds__(512, 2) void attn_kernel(const unsigned short* __restrict__ Kb,
                                                      const unsigned short* __restrict__ Qb,
                                                      const unsigned short* __restrict__ Vt2,
                                                      float* __restrict__ out) {
    __shared__ __attribute__((aligned(16))) float Pacc[16][32][68];  // [slot][q][h] pad 68
    __shared__ float Pml[2][16][32];                                 // m / l per slot,q

    const int t = threadIdx.x;
    const int w = t >> 6, lane = t & 63;
    const int lr = lane & 15, g = lane >> 4;
    const int p = blockIdx.x, b = blockIdx.y;
    const int nhi = 64 - p;                      // steps for hi band
    const int q0h = (63 - p) * 32, q0l = p * 32;
    const size_t rowbase = (size_t)b * 2048;
    const size_t vbase = (size_t)b * 64 * 2048;
    const float NEG_INF = -__builtin_inff();
    const float SCALE2 = 0.03125f * 1.4426950408889634f;   // d^-0.5 * log2(e)

    // Q fragments (B-operand): [sub][hh]
    short8 qfH[2][2], qfL[2][2];
#pragma unroll
    for (int sub = 0; sub < 2; ++sub)
#pragma unroll
        for (int hh = 0; hh < 2; ++hh) {
            qfH[sub][hh] = *(const short8*)(Qb + (rowbase + q0h + 16 * sub + lr) * 64 + 32 * hh + 8 * g);
            qfL[sub][hh] = *(const short8*)(Qb + (rowbase + q0l + 16 * sub + lr) * 64 + 32 * hh + 8 * g);
        }

    f32x4 accH[2][4] = {}, accL[2][4] = {};
    float mH[2] = {NEG_INF, NEG_INF}, mL[2] = {NEG_INF, NEG_INF};
    float lH[2] = {0.f, 0.f}, lL[2] = {0.f, 0.f};

    const int s0 = (w * 65) >> 3, s1 = ((w + 1) * 65) >> 3;

    auto loadS = [&](int kv0, short8 (&kf)[2][2], short8 (&vf)[4]) {
#pragma unroll
        for (int f = 0; f < 2; ++f)
#pragma unroll
            for (int hh = 0; hh < 2; ++hh)
                kf[f][hh] = *(const short8*)(Kb + (rowbase + kv0 + 16 * f + lr) * 64 + 32 * hh + 8 * g);
        // Vt2: one contiguous 16B per frag; e-map identical to P's sigma(g,e)
#pragma unroll
        for (int fh = 0; fh < 4; ++fh)
            vf[fh] = *(const short8*)(Vt2 + vbase + (size_t)(16 * fh + lr) * 2048 + (kv0 >> 5) * 32 + 8 * g);
    };

    auto comp = [&](int kv0, int q0, const short8 (&qf)[2][2],
                    const short8 (&kf)[2][2], const short8 (&vf)[4],
                    f32x4 (&acc)[2][4], float (&m2)[2], float (&ls)[2]) {
#pragma unroll
        for (int sub = 0; sub < 2; ++sub) {
            f32x4 sv[2];
#pragma unroll
            for (int f = 0; f < 2; ++f) {
                f32x4 x = {};
                x = MFMA_16x16x32_BF16(kf[f][0], qf[sub][0], x);
                x = MFMA_16x16x32_BF16(kf[f][1], qf[sub][1], x);
                sv[f] = x;
            }
            const int q = q0 + 16 * sub + lr;
            float pvv[8], tmax = NEG_INF;
#pragma unroll
            for (int f = 0; f < 2; ++f)
#pragma unroll
                for (int r = 0; r < 4; ++r) {
                    int kp = kv0 + 16 * f + 4 * g + r;
                    float sc = sv[f][r] * SCALE2;
                    sc = (kp <= q) ? sc : NEG_INF;
                    pvv[4 * f + r] = sc;
                    tmax = fmaxf(tmax, sc);
                }
            tmax = fmaxf(tmax, __shfl_xor(tmax, 16));
            tmax = fmaxf(tmax, __shfl_xor(tmax, 32));
            float mnew = fmaxf(m2[sub], tmax);     // finite: kv0 <= q0 <= q always
            float alpha = exp2f(m2[sub] - mnew);
            float psum = 0.f;
            short8 pf;
#pragma unroll
            for (int e = 0; e < 8; ++e) {
                float pe = exp2f(pvv[e] - mnew);
                psum += pe;
                pf[e] = (short)f2bf(pe);
            }
            psum += __shfl_xor(psum, 16);
            psum += __shfl_xor(psum, 32);
            ls[sub] = ls[sub] * alpha + psum;
            m2[sub] = mnew;
#pragma unroll
            for (int fh = 0; fh < 4; ++fh) {
                acc[sub][fh][0] *= alpha; acc[sub][fh][1] *= alpha;
                acc[sub][fh][2] *= alpha; acc[sub][fh][3] *= alpha;
                acc[sub][fh] = MFMA_16x16x32_BF16(vf[fh], pf, acc[sub][fh]);
            }
        }
    };

    short8 kfA[2][2], vfA[4], kfB[2][2], vfB[4];

    // ---- hi band (kv0 = s*32) ----
    {
        const int e = (s1 < nhi) ? s1 : nhi;
        int s = s0;
        for (; s + 1 < e; s += 2) {
            loadS(s * 32, kfA, vfA);
            loadS((s + 1) * 32, kfB, vfB);       // flies under comp(A)
            comp(s * 32, q0h, qfH, kfA, vfA, accH, mH, lH);
            comp((s + 1) * 32, q0h, qfH, kfB, vfB, accH, mH, lH);
        }
        if (s < e) {
            loadS(s * 32, kfA, vfA);
            comp(s * 32, q0h, qfH, kfA, vfA, accH, mH, lH);
        }
    }
    // ---- lo band (kv0 = (s-nhi)*32) ----
    {
        int s = (s0 > nhi) ? s0 : nhi;
        for (; s + 1 < s1; s += 2) {
            loadS((s - nhi) * 32, kfA, vfA);
            loadS((s + 1 - nhi) * 32, kfB, vfB);
            comp((s - nhi) * 32, q0l, qfL, kfA, vfA, accL, mL, lL);
            comp((s + 1 - nhi) * 32, q0l, qfL, kfB, vfB, accL, mL, lL);
        }
        if (s < s1) {
            loadS((s - nhi) * 32, kfA, vfA);
            comp((s - nhi) * 32, q0l, qfL, kfA, vfA, accL, mL, lL);
        }
    }

    // ---- write partials to LDS ----
#pragma unroll
    for (int bnd = 0; bnd < 2; ++bnd) {
        const f32x4 (&acc)[2][4] = bnd ? accL : accH;
        const float (&m2)[2] = bnd ? mL : mH;
        const float (&ls)[2] = bnd ? lL : lH;
        const int slot = bnd * 8 + w;
#pragma unroll
        for (int sub = 0; sub < 2; ++sub) {
#pragma unroll
            for (int fh = 0; fh < 4; ++fh)
                *(f32x4*)&Pacc[slot][16 * sub + lr][16 * fh + 4 * g] = acc[sub][fh];
            if (g == 0) {
                Pml[0][slot][16 * sub + lr] = m2[sub];
                Pml[1][slot][16 * sub + lr] = ls[sub];
            }
        }
    }
    __syncthreads();

    // ---- combine: 512 thr -> 2 bands x 32 q x 8 h-groups ----
    {
        const int tb = t >> 8, t2 = t & 255;
        const int qq = t2 & 31, hb = (t2 >> 5) * 8;
        float mw[8], M = NEG_INF;
#pragma unroll
        for (int wv = 0; wv < 8; ++wv) {
            mw[wv] = Pml[0][tb * 8 + wv][qq];
            M = fmaxf(M, mw[wv]);
        }
        float wgt[8], L = 0.f;
#pragma unroll
        for (int wv = 0; wv < 8; ++wv) {
            wgt[wv] = exp2f(mw[wv] - M);           // exp2(-inf)=0 for idle waves
            L += wgt[wv] * Pml[1][tb * 8 + wv][qq];
        }
        f32x4 o0 = {}, o1 = {};
#pragma unroll
        for (int wv = 0; wv < 8; ++wv) {
            f32x4 a0 = *(const f32x4*)&Pacc[tb * 8 + wv][qq][hb];
            f32x4 a1 = *(const f32x4*)&Pacc[tb * 8 + wv][qq][hb + 4];
            o0 += wgt[wv] * a0;
            o1 += wgt[wv] * a1;
        }
        const float invL = 1.f / L;
        o0 *= invL; o1 *= invL;
        const int q0 = tb ? q0l : q0h;
        float* op = out + (rowbase + q0 + qq) * 64 + hb;
        *(f32x4*)op = o0;
        *(f32x4*)(op + 4) = o1;
    }
}

// ---------------------------------------------------------------------------
extern "C" void kernel_launch(void* const* d_in, const int* in_sizes, int n_in,
                              void* d_out, int out_size, void* d_ws, size_t ws_size,
                              hipStream_t stream) {
    const float* X  = (const float*)d_in[0];
    const float* Wk = (const float*)d_in[1];
    const float* Wq = (const float*)d_in[2];
    const float* Wv = (const float*)d_in[3];

    unsigned short* Wt  = (unsigned short*)d_ws;       // 192*1024 bf16 (swizzled)
    unsigned short* Kb  = Wt + 192 * 1024;             // [16384][64] bf16
    unsigned short* Qb  = Kb + 16384 * 64;             // [16384][64] bf16
    unsigned short* Vt2 = Qb + 16384 * 64;             // [8][64][64][32] bf16 (V^T sigma)
    float* out = (float*)d_out;

    wconv_kernel<<<dim3(192), dim3(256), 0, stream>>>(Wk, Wq, Wv, Wt);
    proj_kernel<<<dim3(512), dim3(512), 0, stream>>>(X, Wt, Kb, Qb, Vt2);
    attn_kernel<<<dim3(32, 8), dim3(512), 0, stream>>>(Kb, Qb, Vt2, out);
}